// Round 6
// baseline (322.986 us; speedup 1.0000x reference)
//
#include <hip/hip_runtime.h>
#include <hip/hip_bf16.h>
#include <math.h>

typedef __attribute__((ext_vector_type(8))) short bf16x8;
typedef __attribute__((ext_vector_type(4))) short short4v;
typedef __attribute__((ext_vector_type(4))) float f32x4;
typedef __attribute__((ext_vector_type(16))) float f32x16;

#define MFMA16(a,b,c) __builtin_amdgcn_mfma_f32_16x16x32_bf16(a,b,c,0,0,0)
#define MFMA32(a,b,c) __builtin_amdgcn_mfma_f32_32x32x16_bf16(a,b,c,0,0,0)

__device__ __forceinline__ unsigned short f2bf(float f) {
  union { float f; unsigned u; } v; v.f = f;
  unsigned r = v.u + 0x7FFFu + ((v.u >> 16) & 1u);
  return (unsigned short)(r >> 16);
}

__device__ __forceinline__ unsigned cvt_pk(float lo, float hi) {
  unsigned r;
  asm("v_cvt_pk_bf16_f32 %0, %1, %2" : "=v"(r) : "v"(lo), "v"(hi));
  return r;
}

__device__ __forceinline__ void async_load16(const void* g, void* lds) {
  __builtin_amdgcn_global_load_lds(
      (const __attribute__((address_space(1))) unsigned int*)g,
      (__attribute__((address_space(3))) unsigned int*)lds, 16, 0, 0);
}

__device__ __forceinline__ f32x16 zero16() {
  f32x16 z;
#pragma unroll
  for (int i = 0; i < 16; ++i) z[i] = 0.f;
  return z;
}

// ---------------- RoPE table ----------------
__global__ void rope_table_kernel(float* __restrict__ tc, float* __restrict__ ts) {
  int i = blockIdx.x * 256 + threadIdx.x;
  if (i >= 2048 * 32) return;
  int s = i >> 5, j = i & 31;
  double invf = pow(10000.0, -(double)(2 * j) / 64.0);
  double ang = (double)s * invf;
  tc[i] = (float)cos(ang);
  ts[i] = (float)sin(ang);
}

// ---------------- fp32 -> bf16 elementwise ----------------
__global__ __launch_bounds__(256) void cvt_kernel(const float* __restrict__ in,
                                                  unsigned short* __restrict__ out, int n4) {
  int i = blockIdx.x * 256 + threadIdx.x;
  if (i >= n4) return;
  float4 v = ((const float4*)in)[i];
  short4v o;
  o[0] = (short)f2bf(v.x); o[1] = (short)f2bf(v.y);
  o[2] = (short)f2bf(v.z); o[3] = (short)f2bf(v.w);
  *(short4v*)&out[(size_t)i * 4] = o;
}

// ---------------- fp32 [R][C] -> bf16 [C][R] transpose ----------------
__global__ __launch_bounds__(256) void transpose_cvt(const float* __restrict__ in,
                                                     unsigned short* __restrict__ out,
                                                     int R, int C) {
  __shared__ float tile[32][33];
  const int bx = blockIdx.x * 32, by = blockIdx.y * 32;
  const int tx = threadIdx.x & 31, ty0 = threadIdx.x >> 5;
#pragma unroll
  for (int p = 0; p < 4; ++p) {
    int r = ty0 + p * 8;
    tile[r][tx] = in[(size_t)(by + r) * C + bx + tx];
  }
  __syncthreads();
#pragma unroll
  for (int p = 0; p < 4; ++p) {
    int r = ty0 + p * 8;
    out[(size_t)(bx + r) * R + by + tx] = f2bf(tile[tx][r]);
  }
}

// ---------------- GEMM (m97 structure) ----------------
__global__ __launch_bounds__(256) void gemm_bt(const unsigned short* __restrict__ A,
                                               const unsigned short* __restrict__ Bt,
                                               float* __restrict__ C,
                                               int M, int N, int K) {
  __shared__ unsigned short As[128 * 32];
  __shared__ unsigned short Bs[128 * 32];
  const int t = threadIdx.x, lane = t & 63, wv = t >> 6;
  const int bn = blockIdx.x, bm = blockIdx.y;
  const int m0 = bm * 128, n0 = bn * 128;
  f32x4 acc[4][4];
#pragma unroll
  for (int m = 0; m < 4; ++m)
#pragma unroll
    for (int n = 0; n < 4; ++n) acc[m][n] = (f32x4){0.f, 0.f, 0.f, 0.f};
  const int wr = (wv >> 1) * 64, wc = (wv & 1) * 64;
  const int ar = lane & 15, ak = (lane >> 4) * 8;
  const int srow = lane >> 2, skc = (lane & 3) * 8;
  const int nkt = K >> 5;
  for (int kt = 0; kt < nkt; ++kt) {
    const unsigned short* Ag = A + (size_t)m0 * K + kt * 32;
    const unsigned short* Bg = Bt + (size_t)n0 * K + kt * 32;
#pragma unroll
    for (int p = 0; p < 2; ++p) {
      int c = wv * 2 + p;
      async_load16(Ag + (size_t)(c * 16 + srow) * K + skc, &As[c * 512]);
      async_load16(Bg + (size_t)(c * 16 + srow) * K + skc, &Bs[c * 512]);
    }
    __syncthreads();
    bf16x8 af[4], bfr[4];
#pragma unroll
    for (int m = 0; m < 4; ++m) af[m] = *(const bf16x8*)&As[(wr + m * 16 + ar) * 32 + ak];
#pragma unroll
    for (int n = 0; n < 4; ++n) bfr[n] = *(const bf16x8*)&Bs[(wc + n * 16 + ar) * 32 + ak];
#pragma unroll
    for (int m = 0; m < 4; ++m)
#pragma unroll
      for (int n = 0; n < 4; ++n) acc[m][n] = MFMA16(af[m], bfr[n], acc[m][n]);
    __syncthreads();
  }
#pragma unroll
  for (int m = 0; m < 4; ++m) {
    int row = m0 + wr + m * 16 + (lane >> 4) * 4;
#pragma unroll
    for (int n = 0; n < 4; ++n) {
      int col = n0 + wc + n * 16 + ar;
      float* cp = C + (size_t)row * N + col;
#pragma unroll
      for (int j = 0; j < 4; ++j) cp[(size_t)j * N] = acc[m][n][j];
    }
  }
}

// ---------------- RoPE apply + head split + V transpose ----------------
// Q gets 0.125 * log2(e) prescale (softmax runs in exp2 domain).
__global__ __launch_bounds__(256) void rope_kernel(const float* __restrict__ qkv,
                                                   const float* __restrict__ tc,
                                                   const float* __restrict__ ts,
                                                   unsigned short* __restrict__ qo,
                                                   unsigned short* __restrict__ ko,
                                                   unsigned short* __restrict__ vt) {
  const int S = 2048;
  const int bx = blockIdx.x;
  const int st = bx & 31, bh = bx >> 5;
  const int b = bh >> 4, h = bh & 15;
  const int t = threadIdx.x;
  const int sl = t >> 2, j0 = (t & 3) * 8;
  const int s = st * 64 + sl;
  const float* row = qkv + (size_t)(b * S + s) * 3072;
  float cv[8], sv[8];
#pragma unroll
  for (int i = 0; i < 8; ++i) {
    cv[i] = tc[s * 32 + j0 + i];
    sv[i] = ts[s * 32 + j0 + i];
  }
  __shared__ unsigned short vtile[64][66];
#pragma unroll
  for (int m = 0; m < 2; ++m) {
    const int col0 = m * 1024 + h * 64;
    const float qscale = (m == 0) ? 0.125f * 1.44269504088896340736f : 1.0f;
    float lo[8], hi[8];
#pragma unroll
    for (int i = 0; i < 8; ++i) {
      lo[i] = row[col0 + j0 + i];
      hi[i] = row[col0 + 32 + j0 + i];
    }
    bf16x8 outlo, outhi;
#pragma unroll
    for (int i = 0; i < 8; ++i) {
      outlo[i] = (short)f2bf((lo[i] * cv[i] - hi[i] * sv[i]) * qscale);
      outhi[i] = (short)f2bf((hi[i] * cv[i] + lo[i] * sv[i]) * qscale);
    }
    unsigned short* dst = (m == 0 ? qo : ko) + (size_t)(bh * S + s) * 64;
    *(bf16x8*)&dst[j0] = outlo;
    *(bf16x8*)&dst[32 + j0] = outhi;
  }
  {
    const int col0 = 2048 + h * 64;
#pragma unroll
    for (int i = 0; i < 8; ++i) {
      vtile[j0 + i][sl] = f2bf(row[col0 + j0 + i]);
      vtile[j0 + 32 + i][sl] = f2bf(row[col0 + 32 + j0 + i]);
    }
  }
  __syncthreads();
  {
    const int hd = t >> 2, sc0 = (t & 3) * 16;
    unsigned short* dst = vt + ((size_t)bh * 64 + hd) * S + st * 64 + sc0;
    bf16x8 a, bv;
#pragma unroll
    for (int i = 0; i < 8; ++i) {
      a[i] = (short)vtile[hd][sc0 + i];
      bv[i] = (short)vtile[hd][sc0 + 8 + i];
    }
    *(bf16x8*)&dst[0] = a;
    *(bf16x8*)&dst[8] = bv;
  }
}

// ---------------- attention ----------------
// Dual-chain (gA=idx, gB=63-idx, 33 chain-units/wave), swapped-operand 32x32,
// per-lane scalar softmax (exp2 domain), 2-deep K register pipeline:
// K(kt+1) issued before processing tile kt; V issued at top of each tile.

__device__ __forceinline__ bf16x8 buildP(const unsigned* w, int tt, int hi) {
  const int base = (tt & 1) * 4 + (tt >> 1) * 8;
  unsigned wA = w[base], wB = w[base + 1], wC = w[base + 2], wD = w[base + 3];
  unsigned s1v = __shfl_xor(hi ? wA : wC, 32);
  unsigned s2v = __shfl_xor(hi ? wB : wD, 32);
  union { unsigned u[4]; bf16x8 v; } pw;
  pw.u[0] = hi ? s1v : wA;
  pw.u[1] = hi ? s2v : wB;
  pw.u[2] = hi ? wC : s1v;
  pw.u[3] = hi ? wD : s2v;
  return pw.v;
}

// softmax update (both banks). l_run per-lane half-sums, combined at epilogue.
__device__ __forceinline__ void softmax_chain2(f32x16& s0, f32x16& s1,
                                               float& m_run, float& l_run,
                                               f32x16& a0, f32x16& a1, unsigned* w) {
  float p[8];
#pragma unroll
  for (int i = 0; i < 8; ++i)
    p[i] = fmaxf(fmaxf(s0[2 * i], s0[2 * i + 1]), fmaxf(s1[2 * i], s1[2 * i + 1]));
#pragma unroll
  for (int i = 0; i < 4; ++i) p[i] = fmaxf(p[i], p[i + 4]);
  float mx = fmaxf(fmaxf(p[0], p[1]), fmaxf(p[2], p[3]));
  mx = fmaxf(mx, __shfl_xor(mx, 32));
  const bool defer = __all(mx - m_run <= 8.0f) != 0;
  const float mn = defer ? m_run : fmaxf(m_run, mx);
  float r0 = 0.f, r1 = 0.f, r2 = 0.f, r3 = 0.f;
#pragma unroll
  for (int i = 0; i < 4; ++i) {
    float e0 = exp2f(s0[4 * i + 0] - mn); s0[4 * i + 0] = e0; r0 += e0;
    float e1 = exp2f(s0[4 * i + 1] - mn); s0[4 * i + 1] = e1; r1 += e1;
    float e2 = exp2f(s0[4 * i + 2] - mn); s0[4 * i + 2] = e2; r2 += e2;
    float e3 = exp2f(s0[4 * i + 3] - mn); s0[4 * i + 3] = e3; r3 += e3;
  }
#pragma unroll
  for (int i = 0; i < 4; ++i) {
    float e0 = exp2f(s1[4 * i + 0] - mn); s1[4 * i + 0] = e0; r0 += e0;
    float e1 = exp2f(s1[4 * i + 1] - mn); s1[4 * i + 1] = e1; r1 += e1;
    float e2 = exp2f(s1[4 * i + 2] - mn); s1[4 * i + 2] = e2; r2 += e2;
    float e3 = exp2f(s1[4 * i + 3] - mn); s1[4 * i + 3] = e3; r3 += e3;
  }
  const float rs = (r0 + r1) + (r2 + r3);
  if (defer) {
    l_run += rs;
  } else {
    const float scl = exp2f(m_run - mn);
    m_run = mn;
    l_run = l_run * scl + rs;
#pragma unroll
    for (int r = 0; r < 16; ++r) { a0[r] *= scl; a1[r] *= scl; }
  }
#pragma unroll
  for (int i = 0; i < 8; ++i) {
    w[i] = cvt_pk(s0[2 * i], s0[2 * i + 1]);
    w[8 + i] = cvt_pk(s1[2 * i], s1[2 * i + 1]);
  }
}

__device__ __forceinline__ void load_kf(bf16x8 (&kf)[8], const unsigned short* __restrict__ kb,
                                        int ql, int hi) {
#pragma unroll
  for (int s = 0; s < 4; ++s) {
    kf[s] = *(const bf16x8*)&kb[ql * 64 + s * 16 + hi * 8];
    kf[4 + s] = *(const bf16x8*)&kb[(32 + ql) * 64 + s * 16 + hi * 8];
  }
}

// One 64-key tile. Chain B always active; chain A active while kt <= kA.
// Diagonal mask (kt == kA/kB): key_local > (g&1)*32 + ql, uniform both parities.
__device__ __forceinline__ void process_tile(
    int kt, int kA, int kB, int gA, int gB,
    const bf16x8 (&kf)[8], const unsigned short* __restrict__ vb,
    int ql, int hi,
    const bf16x8 (&qfA)[4], f32x16& aA0, f32x16& aA1, float& mA, float& lA,
    const bf16x8 (&qfB)[4], f32x16& aB0, f32x16& aB1, float& mB, float& lB) {
  const int S = 2048;
  const bool Aon = (kt <= kA);

  // V issued early; consumed after QK+softmax (~600 cy) -> L2 latency hidden
  bf16x8 v0[4], v1[4];
#pragma unroll
  for (int tt = 0; tt < 4; ++tt) {
    v0[tt] = *(const bf16x8*)&vb[(size_t)ql * S + tt * 16 + hi * 8];
    v1[tt] = *(const bf16x8*)&vb[(size_t)(32 + ql) * S + tt * 16 + hi * 8];
  }

  // ---- chain B (QK -> mask -> softmax -> PV), retires wB/sB early ----
  {
    f32x16 s0 = zero16(), s1 = zero16();
    __builtin_amdgcn_s_setprio(1);
#pragma unroll
    for (int s = 0; s < 4; ++s) {
      s0 = MFMA32(kf[s], qfB[s], s0);
      s1 = MFMA32(kf[4 + s], qfB[s], s1);
    }
    __builtin_amdgcn_s_setprio(0);
    if (kt == kB) {
      const int qlit = (gB & 1) * 32 + ql;
#pragma unroll
      for (int r = 0; r < 16; ++r) {
        const int key = (r & 3) + 8 * (r >> 2) + 4 * hi;
        if (key > qlit) s0[r] = -INFINITY;
        if (32 + key > qlit) s1[r] = -INFINITY;
      }
    }
    unsigned wB[16];
    softmax_chain2(s0, s1, mB, lB, aB0, aB1, wB);
    __builtin_amdgcn_s_setprio(1);
#pragma unroll
    for (int tt = 0; tt < 4; ++tt) {
      bf16x8 pB = buildP(wB, tt, hi);
      aB0 = MFMA32(v0[tt], pB, aB0);
      aB1 = MFMA32(v1[tt], pB, aB1);
    }
    __builtin_amdgcn_s_setprio(0);
  }

  // ---- chain A ----
  if (Aon) {
    f32x16 s0 = zero16(), s1 = zero16();
    __builtin_amdgcn_s_setprio(1);
#pragma unroll
    for (int s = 0; s < 4; ++s) {
      s0 = MFMA32(kf[s], qfA[s], s0);
      s1 = MFMA32(kf[4 + s], qfA[s], s1);
    }
    __builtin_amdgcn_s_setprio(0);
    if (kt == kA) {
      const int qlit = (gA & 1) * 32 + ql;
#pragma unroll
      for (int r = 0; r < 16; ++r) {
        const int key = (r & 3) + 8 * (r >> 2) + 4 * hi;
        if (key > qlit) s0[r] = -INFINITY;
        if (32 + key > qlit) s1[r] = -INFINITY;
      }
    }
    unsigned wA[16];
    softmax_chain2(s0, s1, mA, lA, aA0, aA1, wA);
    __builtin_amdgcn_s_setprio(1);
#pragma unroll
    for (int tt = 0; tt < 4; ++tt) {
      bf16x8 pA = buildP(wA, tt, hi);
      aA0 = MFMA32(v0[tt], pA, aA0);
      aA1 = MFMA32(v1[tt], pA, aA1);
    }
    __builtin_amdgcn_s_setprio(0);
  }
}

// grid: 512 blocks (XCD-swizzled); wave (bh, idx): chains gA=idx, gB=63-idx.
__global__ __launch_bounds__(256, 2) void attn_kernel(const unsigned short* __restrict__ Q,
                                                      const unsigned short* __restrict__ Kk,
                                                      const unsigned short* __restrict__ Vt,
                                                      unsigned short* __restrict__ O) {
  const int S = 2048;
  const int t = threadIdx.x, lane = t & 63, wv = t >> 6;
  const int swz = (blockIdx.x & 7) * 64 + (blockIdx.x >> 3);  // XCD-contiguous
  const int bh = swz >> 3, jj = swz & 7;
  const int b = bh >> 4, h = bh & 15;
  const int idx = jj * 4 + wv;          // 0..31
  const int gA = idx, gB = 63 - idx;
  const int kA = gA >> 1, kB = gB >> 1;
  const int ql = lane & 31, hi = lane >> 5;
  const unsigned short* qh = Q + (size_t)bh * S * 64;
  const unsigned short* kh = Kk + (size_t)bh * S * 64;
  const unsigned short* vh = Vt + (size_t)bh * 64 * S;

  bf16x8 qfA[4], qfB[4];
#pragma unroll
  for (int s = 0; s < 4; ++s) {
    qfA[s] = *(const bf16x8*)&qh[(size_t)(32 * gA + ql) * 64 + s * 16 + hi * 8];
    qfB[s] = *(const bf16x8*)&qh[(size_t)(32 * gB + ql) * 64 + s * 16 + hi * 8];
  }

  f32x16 aA0 = zero16(), aA1 = zero16(), aB0 = zero16(), aB1 = zero16();
  float mA = -INFINITY, lA = 0.f, mB = -INFINITY, lB = 0.f;

  // 2-deep K pipeline: K(kt+1) in flight while tile kt computes.
  bf16x8 kf0[8], kf1[8];
  load_kf(kf0, kh, ql, hi);
  int kt = 0;
  while (true) {
    if (kt + 1 <= kB) load_kf(kf1, kh + (size_t)(kt + 1) * 4096, ql, hi);
    process_tile(kt, kA, kB, gA, gB, kf0, vh + kt * 64, ql, hi,
                 qfA, aA0, aA1, mA, lA, qfB, aB0, aB1, mB, lB);
    ++kt;
    if (kt > kB) break;
    if (kt + 1 <= kB) load_kf(kf0, kh + (size_t)(kt + 1) * 4096, ql, hi);
    process_tile(kt, kA, kB, gA, gB, kf1, vh + kt * 64, ql, hi,
                 qfA, aA0, aA1, mA, lA, qfB, aB0, aB1, mB, lB);
    ++kt;
    if (kt > kB) break;
  }

  lA += __shfl_xor(lA, 32);
  lB += __shfl_xor(lB, 32);
  const float invA = 1.f / lA, invB = 1.f / lB;
  unsigned short* orowA = O + (size_t)(b * S + 32 * gA + ql) * 1024 + h * 64;
  unsigned short* orowB = O + (size_t)(b * S + 32 * gB + ql) * 1024 + h * 64;
#pragma unroll
  for (int r = 0; r < 16; ++r) {
    int d = (r & 3) + 8 * (r >> 2) + 4 * hi;
    orowA[d] = f2bf(aA0[r] * invA);
    orowA[32 + d] = f2bf(aA1[r] * invA);
    orowB[d] = f2bf(aB0[r] * invB);
    orowB[32 + d] = f2bf(aB1[r] * invB);
  }
}

extern "C" void kernel_launch(void* const* d_in, const int* in_sizes, int n_in,
                              void* d_out, int out_size, void* d_ws, size_t ws_size,
                              hipStream_t stream) {
  const float* x = (const float*)d_in[0];
  const float* Wqkv = (const float*)d_in[1];
  const float* Wout = (const float*)d_in[2];
  float* out = (float*)d_out;

  char* ws = (char*)d_ws;
  size_t off = 0;
  auto take = [&](size_t bytes) {
    void* p = ws + off;
    off += (bytes + 255) & ~(size_t)255;
    return p;
  };
  float* tc = (float*)take(2048 * 32 * 4);
  float* tsn = (float*)take(2048 * 32 * 4);
  unsigned short* xbf = (unsigned short*)take((size_t)8192 * 1024 * 2);
  unsigned short* wqkvT = (unsigned short*)take((size_t)3072 * 1024 * 2);
  unsigned short* woutT = (unsigned short*)take((size_t)1024 * 1024 * 2);
  float* qkvf = (float*)take((size_t)8192 * 3072 * 4);
  unsigned short* qb_ = (unsigned short*)take((size_t)64 * 2048 * 64 * 2);
  unsigned short* kb_ = (unsigned short*)take((size_t)64 * 2048 * 64 * 2);
  unsigned short* vt = (unsigned short*)take((size_t)64 * 64 * 2048 * 2);
  unsigned short* attn = (unsigned short*)take((size_t)8192 * 1024 * 2);

  rope_table_kernel<<<256, 256, 0, stream>>>(tc, tsn);
  cvt_kernel<<<(2097152 + 255) / 256, 256, 0, stream>>>(x, xbf, 2097152);
  {
    dim3 g(96, 32);
    transpose_cvt<<<g, 256, 0, stream>>>(Wqkv, wqkvT, 1024, 3072);
  }
  {
    dim3 g(32, 32);
    transpose_cvt<<<g, 256, 0, stream>>>(Wout, woutT, 1024, 1024);
  }
  {
    dim3 g(24, 64);
    gemm_bt<<<g, 256, 0, stream>>>(xbf, wqkvT, qkvf, 8192, 3072, 1024);
  }
  rope_kernel<<<2048, 256, 0, stream>>>(qkvf, tc, tsn, qb_, kb_, vt);
  attn_kernel<<<512, 256, 0, stream>>>(qb_, kb_, vt, attn);
  {
    dim3 g(8, 64);
    gemm_bt<<<g, 256, 0, stream>>>(attn, woutT, out, 8192, 1024, 1024);
  }
}